// Round 1
// baseline (769.000 us; speedup 1.0000x reference)
//
#include <hip/hip_runtime.h>

typedef unsigned short u16;
typedef unsigned int u32;
typedef short bf16x8 __attribute__((ext_vector_type(8)));
typedef float f32x4 __attribute__((ext_vector_type(4)));

#define M_ROWS   66096      // 3888 frames * 17 joints
#define M_PAD    66176      // 517 * 128
#define C_DIM    512
#define NQKV     1536
#define NFRAME   3888

// ---------- helpers ----------

__device__ __forceinline__ u16 f2bf(float f) {
    u32 u = __float_as_uint(f);
    u32 r = (u + 0x7fffu + ((u >> 16) & 1u)) >> 16;   // RNE
    return (u16)r;
}
__device__ __forceinline__ float bf2f(u16 v) {
    return __uint_as_float(((u32)v) << 16);
}
__device__ __forceinline__ void async16(const void* g, void* l) {
    __builtin_amdgcn_global_load_lds(
        (const __attribute__((address_space(1))) unsigned int*)g,
        (__attribute__((address_space(3))) unsigned int*)l, 16, 0, 0);
}

// ---------- kernel 1: cast x -> bf16, K-tiled [kt][m][32], zero pad rows ----------

__global__ __launch_bounds__(256) void cast_x(const float* __restrict__ x, u16* __restrict__ xb) {
    u32 cid = blockIdx.x * 256u + threadIdx.x;      // one 8-elem chunk each
    u32 m  = cid >> 6;                              // 64 chunks per 512-row
    u32 c0 = (cid & 63u) * 8u;
    if (m >= M_PAD) return;
    u16 v[8];
    if (m < M_ROWS) {
        const float* p = x + (size_t)m * C_DIM + c0;
        float4 f1 = *(const float4*)p;
        float4 f2 = *(const float4*)(p + 4);
        v[0]=f2bf(f1.x); v[1]=f2bf(f1.y); v[2]=f2bf(f1.z); v[3]=f2bf(f1.w);
        v[4]=f2bf(f2.x); v[5]=f2bf(f2.y); v[6]=f2bf(f2.z); v[7]=f2bf(f2.w);
    } else {
        #pragma unroll
        for (int i = 0; i < 8; ++i) v[i] = 0;
    }
    u16* dst = xb + ((size_t)(c0 >> 5) * M_PAD + m) * 32 + (c0 & 31u);
    *(uint4*)dst = *(const uint4*)v;
}

// ---------- kernel 2: W (K x N) -> bf16 transposed+tiled [kt][n][32] ----------

__global__ __launch_bounds__(256) void cast_w(const float* __restrict__ W, u16* __restrict__ out, int N) {
    __shared__ float tile[32 * 65];
    const int n0 = blockIdx.x * 64;
    const int kt = blockIdx.y;
    const int t  = threadIdx.x;
    for (int i = t; i < 2048; i += 256) {
        int k = i >> 6, n = i & 63;
        tile[k * 65 + n] = W[(size_t)(kt * 32 + k) * N + n0 + n];
    }
    __syncthreads();
    {
        int n = t >> 2, kk0 = (t & 3) * 8;
        u16 v[8];
        #pragma unroll
        for (int j = 0; j < 8; ++j) v[j] = f2bf(tile[(kk0 + j) * 65 + n]);
        u16* dst = out + ((size_t)kt * N + n0 + n) * 32 + kk0;
        *(uint4*)dst = *(const uint4*)v;
    }
}

// ---------- kernel 3: QKV GEMM (66096x512 @ 512x1536) + bias, bf16 out ----------

__global__ __launch_bounds__(256) void gemm1(const u16* __restrict__ xb,   // [16][M_PAD][32]
                                             const u16* __restrict__ wt,   // [16][1536][32]
                                             const float* __restrict__ bqkv,
                                             u16* __restrict__ qkv) {      // [M_PAD][1536]
    __shared__ u16 As[128 * 32];
    __shared__ u16 Bs[128 * 32];
    __shared__ float biasS[128];

    const int n0 = blockIdx.x * 128;
    const int m0 = blockIdx.y * 128;
    const int t  = threadIdx.x;
    const int w  = t >> 6, l = t & 63;
    const int lr = l & 15, lq = l >> 4;
    const int wr = (w >> 1) * 64, wc = (w & 1) * 64;

    if (t < 128) biasS[t] = bqkv[n0 + t];

    f32x4 acc[4][4] = {};

    for (int kt = 0; kt < 16; ++kt) {
        __syncthreads();
        const u16* ga = xb + ((size_t)kt * M_PAD + m0) * 32;
        const u16* gb = wt + ((size_t)kt * NQKV + n0) * 32;
        async16(ga + (size_t)t * 8,         &As[t * 8]);
        async16(ga + (size_t)(t + 256) * 8, &As[(t + 256) * 8]);
        async16(gb + (size_t)t * 8,         &Bs[t * 8]);
        async16(gb + (size_t)(t + 256) * 8, &Bs[(t + 256) * 8]);
        __syncthreads();

        bf16x8 a[4], b[4];
        #pragma unroll
        for (int i = 0; i < 4; ++i) a[i] = *(const bf16x8*)&As[(wr + i * 16 + lr) * 32 + lq * 8];
        #pragma unroll
        for (int i = 0; i < 4; ++i) b[i] = *(const bf16x8*)&Bs[(wc + i * 16 + lr) * 32 + lq * 8];
        #pragma unroll
        for (int i = 0; i < 4; ++i)
            #pragma unroll
            for (int j = 0; j < 4; ++j)
                acc[i][j] = __builtin_amdgcn_mfma_f32_16x16x32_bf16(a[i], b[j], acc[i][j], 0, 0, 0);
    }

    #pragma unroll
    for (int i = 0; i < 4; ++i) {
        #pragma unroll
        for (int j = 0; j < 4; ++j) {
            const int col  = n0 + wc + j * 16 + lr;
            const float bb = biasS[wc + j * 16 + lr];
            #pragma unroll
            for (int r = 0; r < 4; ++r) {
                const int row = m0 + wr + i * 16 + lq * 4 + r;
                if (row < M_ROWS)
                    qkv[(size_t)row * NQKV + col] = f2bf(acc[i][j][r] + bb);
            }
        }
    }
}

// ---------- kernel 4: per-frame attention with hierarchical triplets ----------

__constant__ int TRJP[13] = {0,1,0,4,0,7,8,7,8,11,7,8,14};
__constant__ int TRJ [13] = {1,2,4,5,7,8,9,8,11,12,8,14,15};
__constant__ int TRJC[13] = {2,3,5,6,8,9,10,11,12,13,14,15,16};

__device__ __forceinline__ float dot8(uint4 qa, uint4 kb) {
    const u32* qu = (const u32*)&qa;
    const u32* ku = (const u32*)&kb;
    float s = 0.f;
    #pragma unroll
    for (int i = 0; i < 4; ++i) {
        float q0 = __uint_as_float(qu[i] << 16);
        float q1 = __uint_as_float(qu[i] & 0xffff0000u);
        float k0 = __uint_as_float(ku[i] << 16);
        float k1 = __uint_as_float(ku[i] & 0xffff0000u);
        s = fmaf(q0, k0, s);
        s = fmaf(q1, k1, s);
    }
    return s;
}

#define QKROW 1552   // 1536 + 16 pad elems -> +8 bank shift per row

__global__ __launch_bounds__(256) void attn_k(const u16* __restrict__ qkv, u16* __restrict__ xa) {
    __shared__ u16 qk[17 * QKROW];
    __shared__ float S[4][17 * 18];

    const int f = blockIdx.x;
    const int t = threadIdx.x;
    const int w = t >> 6, l = t & 63;
    const u16* src = qkv + (size_t)f * 17 * NQKV;

    for (int i = t; i < 3264; i += 256) {            // 17*1536/8 chunks
        int r = i / 192, c = i - r * 192;
        *(uint4*)&qk[r * QKROW + c * 8] = *(const uint4*)&src[i * 8];
    }
    __syncthreads();

    for (int hh = 0; hh < 2; ++hh) {
        const int h = hh * 4 + w;
        float* Sw = S[w];

        // S = (Q K^T) * scale
        for (int e = l; e < 289; e += 64) {
            int qi = e / 17, ki = e - qi * 17;
            const u16* qp = &qk[qi * QKROW + h * 64];
            const u16* kp = &qk[ki * QKROW + 512 + h * 64];
            float d = 0.f;
            #pragma unroll
            for (int c = 0; c < 8; ++c)
                d += dot8(*(const uint4*)&qp[c * 8], *(const uint4*)&kp[c * 8]);
            Sw[qi * 18 + ki] = d * 0.125f;
        }
        __syncthreads();

        // softmax rows (lane j handles row j)
        if (l < 17) {
            float mx = -1e30f;
            #pragma unroll
            for (int k = 0; k < 17; ++k) mx = fmaxf(mx, Sw[l * 18 + k]);
            float s = 0.f;
            #pragma unroll
            for (int k = 0; k < 17; ++k) {
                float e = __expf(Sw[l * 18 + k] - mx);
                Sw[l * 18 + k] = e;
                s += e;
            }
            float inv = 1.f / s;
            #pragma unroll
            for (int k = 0; k < 17; ++k) Sw[l * 18 + k] *= inv;
        }
        __syncthreads();

        // sequential hierarchical adjustment (order matters)
        if (l == 0) {
            #pragma unroll
            for (int tr = 0; tr < 13; ++tr) {
                int jp = TRJP[tr], j = TRJ[tr], jc = TRJC[tr];
                float half = Sw[j * 18 + jp] * 0.5f;
                Sw[j * 18 + jc] += half;
                Sw[jc * 18 + j] += half;
            }
        }
        __syncthreads();

        // out[j][d] = sum_k P[j][k] * V[k][d], lane = d
        float vreg[17];
        #pragma unroll
        for (int k = 0; k < 17; ++k) vreg[k] = bf2f(qk[k * QKROW + 1024 + h * 64 + l]);
        const int col = h * 64 + l;
        u16* dst = xa + ((size_t)(col >> 5) * M_PAD) * 32 + (col & 31);
        #pragma unroll
        for (int j = 0; j < 17; ++j) {
            float o = 0.f;
            #pragma unroll
            for (int k = 0; k < 17; ++k) o = fmaf(Sw[j * 18 + k], vreg[k], o);
            const int row = f * 17 + j;
            dst[(size_t)row * 32] = f2bf(o);
        }
        __syncthreads();
    }
}

// ---------- kernel 5: proj GEMM + bias + residual + LayerNorm ----------

__global__ __launch_bounds__(256) void gemm2(const u16* __restrict__ xa,  // [16][M_PAD][32]
                                             const u16* __restrict__ wt,  // [16][512][32]
                                             const float* __restrict__ bproj,
                                             const float* __restrict__ x,
                                             float* __restrict__ out) {
    __shared__ u16 As[32 * 32];
    __shared__ u16 Bs[512 * 32];
    __shared__ float biasS[512];
    __shared__ float ssum[32], ssq[32];

    const int m0 = blockIdx.x * 32;
    const int t  = threadIdx.x;
    const int w  = t >> 6, l = t & 63;
    const int lr = l & 15, lq = l >> 4;

    for (int i = t; i < 512; i += 256) biasS[i] = bproj[i];
    if (t < 32) { ssum[t] = 0.f; ssq[t] = 0.f; }

    f32x4 acc[2][8] = {};

    for (int kt = 0; kt < 16; ++kt) {
        __syncthreads();
        const u16* ga = xa + ((size_t)kt * M_PAD + m0) * 32;
        const u16* gb = wt + (size_t)kt * 512 * 32;
        if (t < 128) async16(ga + (size_t)t * 8, &As[t * 8]);
        #pragma unroll
        for (int i = 0; i < 8; ++i)
            async16(gb + (size_t)(t + 256 * i) * 8, &Bs[(t + 256 * i) * 8]);
        __syncthreads();

        bf16x8 a[2], b[8];
        #pragma unroll
        for (int i = 0; i < 2; ++i) a[i] = *(const bf16x8*)&As[(i * 16 + lr) * 32 + lq * 8];
        #pragma unroll
        for (int j = 0; j < 8; ++j) b[j] = *(const bf16x8*)&Bs[((w << 7) + j * 16 + lr) * 32 + lq * 8];
        #pragma unroll
        for (int i = 0; i < 2; ++i)
            #pragma unroll
            for (int j = 0; j < 8; ++j)
                acc[i][j] = __builtin_amdgcn_mfma_f32_16x16x32_bf16(a[i], b[j], acc[i][j], 0, 0, 0);
    }

    // epilogue: y = acc + bias + x; per-row stats via shfl + LDS atomics
    #pragma unroll
    for (int i = 0; i < 2; ++i) {
        #pragma unroll
        for (int r = 0; r < 4; ++r) {
            const int row = m0 + i * 16 + lq * 4 + r;
            const bool valid = row < M_ROWS;
            float s = 0.f, sq = 0.f;
            #pragma unroll
            for (int j = 0; j < 8; ++j) {
                const int col = (w << 7) + j * 16 + lr;
                float v = acc[i][j][r] + biasS[col];
                if (valid) v += x[(size_t)row * C_DIM + col];
                acc[i][j][r] = v;
                s += v;
                sq = fmaf(v, v, sq);
            }
            #pragma unroll
            for (int m = 1; m < 16; m <<= 1) {
                s  += __shfl_xor(s, m);
                sq += __shfl_xor(sq, m);
            }
            if (lr == 0) {
                atomicAdd(&ssum[i * 16 + lq * 4 + r], s);
                atomicAdd(&ssq [i * 16 + lq * 4 + r], sq);
            }
        }
    }
    __syncthreads();

    #pragma unroll
    for (int i = 0; i < 2; ++i) {
        #pragma unroll
        for (int r = 0; r < 4; ++r) {
            const int row = m0 + i * 16 + lq * 4 + r;
            if (row >= M_ROWS) continue;
            const int li = i * 16 + lq * 4 + r;
            const float mean = ssum[li] * (1.f / 512.f);
            const float var  = ssq[li] * (1.f / 512.f) - mean * mean;
            const float rstd = rsqrtf(var + 1e-5f);
            #pragma unroll
            for (int j = 0; j < 8; ++j) {
                const int col = (w << 7) + j * 16 + lr;
                out[(size_t)row * C_DIM + col] = (acc[i][j][r] - mean) * rstd;
            }
        }
    }
}

// ---------- launch ----------

extern "C" void kernel_launch(void* const* d_in, const int* in_sizes, int n_in,
                              void* d_out, int out_size, void* d_ws, size_t ws_size,
                              hipStream_t stream) {
    const float* x     = (const float*)d_in[0];
    const float* Wqkv  = (const float*)d_in[1];
    const float* bqkv  = (const float*)d_in[2];
    const float* Wproj = (const float*)d_in[3];
    const float* bproj = (const float*)d_in[4];
    float* out = (float*)d_out;

    u16* xb  = (u16*)d_ws;                              // M_PAD*512
    u16* wqt = xb  + (size_t)M_PAD * C_DIM;             // 1536*512
    u16* wpt = wqt + (size_t)NQKV * C_DIM;              // 512*512
    u16* qkv = wpt + (size_t)C_DIM * C_DIM;             // M_PAD*1536
    u16* xa  = qkv + (size_t)M_PAD * NQKV;              // M_PAD*512

    cast_x<<<(M_PAD * 64) / 256, 256, 0, stream>>>(x, xb);
    cast_w<<<dim3(NQKV / 64, 16), 256, 0, stream>>>(Wqkv, wqt, NQKV);
    cast_w<<<dim3(C_DIM / 64, 16), 256, 0, stream>>>(Wproj, wpt, C_DIM);
    gemm1<<<dim3(NQKV / 128, M_PAD / 128), 256, 0, stream>>>(xb, wqt, bqkv, qkv);
    attn_k<<<NFRAME, 256, 0, stream>>>(qkv, xa);
    gemm2<<<(M_ROWS + 31) / 32, 256, 0, stream>>>(xa, wpt, bproj, x, out);
}

// Round 2
// 743.811 us; speedup vs baseline: 1.0339x; 1.0339x over previous
//
#include <hip/hip_runtime.h>

typedef unsigned short u16;
typedef unsigned int u32;
typedef short bf16x8 __attribute__((ext_vector_type(8)));
typedef float f32x4 __attribute__((ext_vector_type(4)));

#define M_ROWS   66096      // 3888 frames * 17 joints
#define M_PAD    66176      // 517 * 128
#define C_DIM    512
#define NQKV     1536
#define NFRAME   3888

// ---------- helpers ----------

__device__ __forceinline__ u16 f2bf(float f) {
    u32 u = __float_as_uint(f);
    u32 r = (u + 0x7fffu + ((u >> 16) & 1u)) >> 16;   // RNE
    return (u16)r;
}
__device__ __forceinline__ float bf2f(u16 v) {
    return __uint_as_float(((u32)v) << 16);
}
__device__ __forceinline__ void async16(const void* g, void* l) {
    __builtin_amdgcn_global_load_lds(
        (const __attribute__((address_space(1))) unsigned int*)g,
        (__attribute__((address_space(3))) unsigned int*)l, 16, 0, 0);
}

// ---------- kernel 1: cast x -> bf16, K-tiled [kt][m][32], zero pad rows ----------

__global__ __launch_bounds__(256) void cast_x(const float* __restrict__ x, u16* __restrict__ xb) {
    u32 cid = blockIdx.x * 256u + threadIdx.x;      // one 8-elem chunk each
    u32 m  = cid >> 6;                              // 64 chunks per 512-row
    u32 c0 = (cid & 63u) * 8u;
    if (m >= M_PAD) return;
    u16 v[8];
    if (m < M_ROWS) {
        const float* p = x + (size_t)m * C_DIM + c0;
        float4 f1 = *(const float4*)p;
        float4 f2 = *(const float4*)(p + 4);
        v[0]=f2bf(f1.x); v[1]=f2bf(f1.y); v[2]=f2bf(f1.z); v[3]=f2bf(f1.w);
        v[4]=f2bf(f2.x); v[5]=f2bf(f2.y); v[6]=f2bf(f2.z); v[7]=f2bf(f2.w);
    } else {
        #pragma unroll
        for (int i = 0; i < 8; ++i) v[i] = 0;
    }
    u16* dst = xb + ((size_t)(c0 >> 5) * M_PAD + m) * 32 + (c0 & 31u);
    *(uint4*)dst = *(const uint4*)v;
}

// ---------- kernel 2: W (K x N) -> bf16 transposed+tiled [kt][n][32] ----------

__global__ __launch_bounds__(256) void cast_w(const float* __restrict__ W, u16* __restrict__ out, int N) {
    __shared__ float tile[32 * 65];
    const int n0 = blockIdx.x * 64;
    const int kt = blockIdx.y;
    const int t  = threadIdx.x;
    for (int i = t; i < 2048; i += 256) {
        int k = i >> 6, n = i & 63;
        tile[k * 65 + n] = W[(size_t)(kt * 32 + k) * N + n0 + n];
    }
    __syncthreads();
    {
        int n = t >> 2, kk0 = (t & 3) * 8;
        u16 v[8];
        #pragma unroll
        for (int j = 0; j < 8; ++j) v[j] = f2bf(tile[(kk0 + j) * 65 + n]);
        u16* dst = out + ((size_t)kt * N + n0 + n) * 32 + kk0;
        *(uint4*)dst = *(const uint4*)v;
    }
}

// ---------- kernel 3: QKV GEMM (66096x512 @ 512x1536) + bias, bf16 out ----------

__global__ __launch_bounds__(256) void gemm1(const u16* __restrict__ xb,   // [16][M_PAD][32]
                                             const u16* __restrict__ wt,   // [16][1536][32]
                                             const float* __restrict__ bqkv,
                                             u16* __restrict__ qkv) {      // [M_PAD][1536]
    __shared__ u16 As[128 * 32];
    __shared__ u16 Bs[128 * 32];
    __shared__ float biasS[128];

    const int n0 = blockIdx.x * 128;
    const int m0 = blockIdx.y * 128;
    const int t  = threadIdx.x;
    const int w  = t >> 6, l = t & 63;
    const int lr = l & 15, lq = l >> 4;
    const int wr = (w >> 1) * 64, wc = (w & 1) * 64;

    if (t < 128) biasS[t] = bqkv[n0 + t];

    f32x4 acc[4][4] = {};

    for (int kt = 0; kt < 16; ++kt) {
        __syncthreads();
        const u16* ga = xb + ((size_t)kt * M_PAD + m0) * 32;
        const u16* gb = wt + ((size_t)kt * NQKV + n0) * 32;
        async16(ga + (size_t)t * 8,         &As[t * 8]);
        async16(ga + (size_t)(t + 256) * 8, &As[(t + 256) * 8]);
        async16(gb + (size_t)t * 8,         &Bs[t * 8]);
        async16(gb + (size_t)(t + 256) * 8, &Bs[(t + 256) * 8]);
        __syncthreads();

        bf16x8 a[4], b[4];
        #pragma unroll
        for (int i = 0; i < 4; ++i) a[i] = *(const bf16x8*)&As[(wr + i * 16 + lr) * 32 + lq * 8];
        #pragma unroll
        for (int i = 0; i < 4; ++i) b[i] = *(const bf16x8*)&Bs[(wc + i * 16 + lr) * 32 + lq * 8];
        #pragma unroll
        for (int i = 0; i < 4; ++i)
            #pragma unroll
            for (int j = 0; j < 4; ++j)
                acc[i][j] = __builtin_amdgcn_mfma_f32_16x16x32_bf16(a[i], b[j], acc[i][j], 0, 0, 0);
    }

    #pragma unroll
    for (int i = 0; i < 4; ++i) {
        #pragma unroll
        for (int j = 0; j < 4; ++j) {
            const int col  = n0 + wc + j * 16 + lr;
            const float bb = biasS[wc + j * 16 + lr];
            #pragma unroll
            for (int r = 0; r < 4; ++r) {
                const int row = m0 + wr + i * 16 + lq * 4 + r;
                if (row < M_ROWS)
                    qkv[(size_t)row * NQKV + col] = f2bf(acc[i][j][r] + bb);
            }
        }
    }
}

// ---------- kernel 4: per-frame attention with hierarchical triplets ----------

__constant__ int TRJP[13] = {0,1,0,4,0,7,8,7,8,11,7,8,14};
__constant__ int TRJ [13] = {1,2,4,5,7,8,9,8,11,12,8,14,15};
__constant__ int TRJC[13] = {2,3,5,6,8,9,10,11,12,13,14,15,16};

__device__ __forceinline__ float dot8(uint4 qa, uint4 kb) {
    const u32* qu = (const u32*)&qa;
    const u32* ku = (const u32*)&kb;
    float s = 0.f;
    #pragma unroll
    for (int i = 0; i < 4; ++i) {
        float q0 = __uint_as_float(qu[i] << 16);
        float q1 = __uint_as_float(qu[i] & 0xffff0000u);
        float k0 = __uint_as_float(ku[i] << 16);
        float k1 = __uint_as_float(ku[i] & 0xffff0000u);
        s = fmaf(q0, k0, s);
        s = fmaf(q1, k1, s);
    }
    return s;
}

#define QKROW 1552   // 1536 + 16 pad elems -> +8 bank shift per row

__global__ __launch_bounds__(256) void attn_k(const u16* __restrict__ qkv, u16* __restrict__ xa) {
    __shared__ u16 qk[17 * QKROW];
    __shared__ float S[4][17 * 18];

    const int f = blockIdx.x;
    const int t = threadIdx.x;
    const int w = t >> 6, l = t & 63;
    const u16* src = qkv + (size_t)f * 17 * NQKV;

    for (int i = t; i < 3264; i += 256) {            // 17*1536/8 chunks
        int r = i / 192, c = i - r * 192;
        *(uint4*)&qk[r * QKROW + c * 8] = *(const uint4*)&src[i * 8];
    }
    __syncthreads();

    for (int hh = 0; hh < 2; ++hh) {
        const int h = hh * 4 + w;
        float* Sw = S[w];

        // S = (Q K^T) * scale
        for (int e = l; e < 289; e += 64) {
            int qi = e / 17, ki = e - qi * 17;
            const u16* qp = &qk[qi * QKROW + h * 64];
            const u16* kp = &qk[ki * QKROW + 512 + h * 64];
            float d = 0.f;
            #pragma unroll
            for (int c = 0; c < 8; ++c)
                d += dot8(*(const uint4*)&qp[c * 8], *(const uint4*)&kp[c * 8]);
            Sw[qi * 18 + ki] = d * 0.125f;
        }
        __syncthreads();

        // softmax rows (lane j handles row j)
        if (l < 17) {
            float mx = -1e30f;
            #pragma unroll
            for (int k = 0; k < 17; ++k) mx = fmaxf(mx, Sw[l * 18 + k]);
            float s = 0.f;
            #pragma unroll
            for (int k = 0; k < 17; ++k) {
                float e = __expf(Sw[l * 18 + k] - mx);
                Sw[l * 18 + k] = e;
                s += e;
            }
            float inv = 1.f / s;
            #pragma unroll
            for (int k = 0; k < 17; ++k) Sw[l * 18 + k] *= inv;
        }
        __syncthreads();

        // sequential hierarchical adjustment (order matters)
        if (l == 0) {
            #pragma unroll
            for (int tr = 0; tr < 13; ++tr) {
                int jp = TRJP[tr], j = TRJ[tr], jc = TRJC[tr];
                float half = Sw[j * 18 + jp] * 0.5f;
                Sw[j * 18 + jc] += half;
                Sw[jc * 18 + j] += half;
            }
        }
        __syncthreads();

        // out[j][d] = sum_k P[j][k] * V[k][d], lane = d
        float vreg[17];
        #pragma unroll
        for (int k = 0; k < 17; ++k) vreg[k] = bf2f(qk[k * QKROW + 1024 + h * 64 + l]);
        const int col = h * 64 + l;
        u16* dst = xa + ((size_t)(col >> 5) * M_PAD) * 32 + (col & 31);
        #pragma unroll
        for (int j = 0; j < 17; ++j) {
            float o = 0.f;
            #pragma unroll
            for (int k = 0; k < 17; ++k) o = fmaf(Sw[j * 18 + k], vreg[k], o);
            const int row = f * 17 + j;
            dst[(size_t)row * 32] = f2bf(o);
        }
        __syncthreads();
    }
}

// ---------- kernel 5: proj GEMM (128x128 tile) + bias + residual -> y fp32 ----------

__global__ __launch_bounds__(256) void gemm2_gemm(const u16* __restrict__ xa,  // [16][M_PAD][32]
                                                  const u16* __restrict__ wt,  // [16][512][32]
                                                  const float* __restrict__ bproj,
                                                  const float* __restrict__ x,
                                                  float* __restrict__ y) {
    __shared__ u16 As[128 * 32];
    __shared__ u16 Bs[128 * 32];
    __shared__ float biasS[128];

    const int n0 = blockIdx.x * 128;
    const int m0 = blockIdx.y * 128;
    const int t  = threadIdx.x;
    const int w  = t >> 6, l = t & 63;
    const int lr = l & 15, lq = l >> 4;
    const int wr = (w >> 1) * 64, wc = (w & 1) * 64;

    if (t < 128) biasS[t] = bproj[n0 + t];

    f32x4 acc[4][4] = {};

    for (int kt = 0; kt < 16; ++kt) {
        __syncthreads();
        const u16* ga = xa + ((size_t)kt * M_PAD + m0) * 32;
        const u16* gb = wt + ((size_t)kt * C_DIM + n0) * 32;
        async16(ga + (size_t)t * 8,         &As[t * 8]);
        async16(ga + (size_t)(t + 256) * 8, &As[(t + 256) * 8]);
        async16(gb + (size_t)t * 8,         &Bs[t * 8]);
        async16(gb + (size_t)(t + 256) * 8, &Bs[(t + 256) * 8]);
        __syncthreads();

        bf16x8 a[4], b[4];
        #pragma unroll
        for (int i = 0; i < 4; ++i) a[i] = *(const bf16x8*)&As[(wr + i * 16 + lr) * 32 + lq * 8];
        #pragma unroll
        for (int i = 0; i < 4; ++i) b[i] = *(const bf16x8*)&Bs[(wc + i * 16 + lr) * 32 + lq * 8];
        #pragma unroll
        for (int i = 0; i < 4; ++i)
            #pragma unroll
            for (int j = 0; j < 4; ++j)
                acc[i][j] = __builtin_amdgcn_mfma_f32_16x16x32_bf16(a[i], b[j], acc[i][j], 0, 0, 0);
    }

    // y = acc + bias + x (residual), fp32
    #pragma unroll
    for (int i = 0; i < 4; ++i) {
        #pragma unroll
        for (int j = 0; j < 4; ++j) {
            const int col  = n0 + wc + j * 16 + lr;
            const float bb = biasS[wc + j * 16 + lr];
            #pragma unroll
            for (int r = 0; r < 4; ++r) {
                const int row = m0 + wr + i * 16 + lq * 4 + r;
                if (row < M_ROWS) {
                    const size_t idx = (size_t)row * C_DIM + col;
                    y[idx] = acc[i][j][r] + bb + x[idx];
                }
            }
        }
    }
}

// ---------- kernel 6: LayerNorm over last dim (512), one wave per row ----------

__global__ __launch_bounds__(256) void ln_k(const float* __restrict__ y, float* __restrict__ out) {
    const int row = blockIdx.x * 4 + (threadIdx.x >> 6);
    const int l   = threadIdx.x & 63;
    const float* p = y + (size_t)row * C_DIM + l * 8;
    float4 a = *(const float4*)p;
    float4 b = *(const float4*)(p + 4);
    float s  = a.x + a.y + a.z + a.w + b.x + b.y + b.z + b.w;
    float sq = a.x*a.x + a.y*a.y + a.z*a.z + a.w*a.w
             + b.x*b.x + b.y*b.y + b.z*b.z + b.w*b.w;
    #pragma unroll
    for (int m = 1; m < 64; m <<= 1) {
        s  += __shfl_xor(s, m);
        sq += __shfl_xor(sq, m);
    }
    const float mean = s * (1.f / 512.f);
    const float var  = sq * (1.f / 512.f) - mean * mean;
    const float rstd = rsqrtf(var + 1e-5f);
    float* q = out + (size_t)row * C_DIM + l * 8;
    float4 o1, o2;
    o1.x = (a.x - mean) * rstd; o1.y = (a.y - mean) * rstd;
    o1.z = (a.z - mean) * rstd; o1.w = (a.w - mean) * rstd;
    o2.x = (b.x - mean) * rstd; o2.y = (b.y - mean) * rstd;
    o2.z = (b.z - mean) * rstd; o2.w = (b.w - mean) * rstd;
    *(float4*)q = o1;
    *(float4*)(q + 4) = o2;
}

// ---------- launch ----------

extern "C" void kernel_launch(void* const* d_in, const int* in_sizes, int n_in,
                              void* d_out, int out_size, void* d_ws, size_t ws_size,
                              hipStream_t stream) {
    const float* x     = (const float*)d_in[0];
    const float* Wqkv  = (const float*)d_in[1];
    const float* bqkv  = (const float*)d_in[2];
    const float* Wproj = (const float*)d_in[3];
    const float* bproj = (const float*)d_in[4];
    float* out = (float*)d_out;

    u16* xb  = (u16*)d_ws;                              // M_PAD*512
    u16* wqt = xb  + (size_t)M_PAD * C_DIM;             // 1536*512
    u16* wpt = wqt + (size_t)NQKV * C_DIM;              // 512*512
    u16* qkv = wpt + (size_t)C_DIM * C_DIM;             // M_PAD*1536 (bf16)
    u16* xa  = qkv + (size_t)M_PAD * NQKV;              // M_PAD*512
    // y (fp32, M_ROWS*512 = 135 MB) reuses the qkv region (203 MB, dead after attn)
    float* y = (float*)qkv;

    cast_x<<<(M_PAD * 64) / 256, 256, 0, stream>>>(x, xb);
    cast_w<<<dim3(NQKV / 64, 16), 256, 0, stream>>>(Wqkv, wqt, NQKV);
    cast_w<<<dim3(C_DIM / 64, 16), 256, 0, stream>>>(Wproj, wpt, C_DIM);
    gemm1<<<dim3(NQKV / 128, M_PAD / 128), 256, 0, stream>>>(xb, wqt, bqkv, qkv);
    attn_k<<<NFRAME, 256, 0, stream>>>(qkv, xa);
    gemm2_gemm<<<dim3(C_DIM / 128, M_PAD / 128), 256, 0, stream>>>(xa, wpt, bproj, x, y);
    ln_k<<<M_ROWS / 4, 256, 0, stream>>>(y, out);
}

// Round 3
// 657.011 us; speedup vs baseline: 1.1705x; 1.1321x over previous
//
#include <hip/hip_runtime.h>

typedef unsigned short u16;
typedef unsigned int u32;
typedef short bf16x8 __attribute__((ext_vector_type(8)));
typedef float f32x4 __attribute__((ext_vector_type(4)));
typedef float f32x16 __attribute__((ext_vector_type(16)));

#define M_ROWS   66096      // 3888 frames * 17 joints
#define M_PAD    66176      // 517 * 128
#define C_DIM    512
#define NQKV     1536
#define NFRAME   3888

// ---------- helpers ----------

__device__ __forceinline__ u16 f2bf(float f) {
    u32 u = __float_as_uint(f);
    u32 r = (u + 0x7fffu + ((u >> 16) & 1u)) >> 16;   // RNE
    return (u16)r;
}
__device__ __forceinline__ float bf2f(u16 v) {
    return __uint_as_float(((u32)v) << 16);
}
__device__ __forceinline__ void async16(const void* g, void* l) {
    __builtin_amdgcn_global_load_lds(
        (const __attribute__((address_space(1))) unsigned int*)g,
        (__attribute__((address_space(3))) unsigned int*)l, 16, 0, 0);
}

// ---------- kernel 1: cast x -> bf16, K-tiled [kt][m][32], zero pad rows ----------

__global__ __launch_bounds__(256) void cast_x(const float* __restrict__ x, u16* __restrict__ xb) {
    u32 cid = blockIdx.x * 256u + threadIdx.x;      // one 8-elem chunk each
    u32 m  = cid >> 6;                              // 64 chunks per 512-row
    u32 c0 = (cid & 63u) * 8u;
    if (m >= M_PAD) return;
    u16 v[8];
    if (m < M_ROWS) {
        const float* p = x + (size_t)m * C_DIM + c0;
        float4 f1 = *(const float4*)p;
        float4 f2 = *(const float4*)(p + 4);
        v[0]=f2bf(f1.x); v[1]=f2bf(f1.y); v[2]=f2bf(f1.z); v[3]=f2bf(f1.w);
        v[4]=f2bf(f2.x); v[5]=f2bf(f2.y); v[6]=f2bf(f2.z); v[7]=f2bf(f2.w);
    } else {
        #pragma unroll
        for (int i = 0; i < 8; ++i) v[i] = 0;
    }
    u16* dst = xb + ((size_t)(c0 >> 5) * M_PAD + m) * 32 + (c0 & 31u);
    *(uint4*)dst = *(const uint4*)v;
}

// ---------- kernel 2: W (K x N) -> bf16 transposed+tiled [kt][n][32] ----------

__global__ __launch_bounds__(256) void cast_w(const float* __restrict__ W, u16* __restrict__ out, int N) {
    __shared__ float tile[32 * 65];
    const int n0 = blockIdx.x * 64;
    const int kt = blockIdx.y;
    const int t  = threadIdx.x;
    for (int i = t; i < 2048; i += 256) {
        int k = i >> 6, n = i & 63;
        tile[k * 65 + n] = W[(size_t)(kt * 32 + k) * N + n0 + n];
    }
    __syncthreads();
    {
        int n = t >> 2, kk0 = (t & 3) * 8;
        u16 v[8];
        #pragma unroll
        for (int j = 0; j < 8; ++j) v[j] = f2bf(tile[(kk0 + j) * 65 + n]);
        u16* dst = out + ((size_t)kt * N + n0 + n) * 32 + kk0;
        *(uint4*)dst = *(const uint4*)v;
    }
}

// ---------- kernel 3: QKV GEMM (66096x512 @ 512x1536) + bias, bf16 out ----------

__global__ __launch_bounds__(256) void gemm1(const u16* __restrict__ xb,   // [16][M_PAD][32]
                                             const u16* __restrict__ wt,   // [16][1536][32]
                                             const float* __restrict__ bqkv,
                                             u16* __restrict__ qkv) {      // [M_PAD][1536]
    __shared__ u16 As[128 * 32];
    __shared__ u16 Bs[128 * 32];
    __shared__ float biasS[128];

    const int n0 = blockIdx.x * 128;
    const int m0 = blockIdx.y * 128;
    const int t  = threadIdx.x;
    const int w  = t >> 6, l = t & 63;
    const int lr = l & 15, lq = l >> 4;
    const int wr = (w >> 1) * 64, wc = (w & 1) * 64;

    if (t < 128) biasS[t] = bqkv[n0 + t];

    f32x4 acc[4][4] = {};

    for (int kt = 0; kt < 16; ++kt) {
        __syncthreads();
        const u16* ga = xb + ((size_t)kt * M_PAD + m0) * 32;
        const u16* gb = wt + ((size_t)kt * NQKV + n0) * 32;
        async16(ga + (size_t)t * 8,         &As[t * 8]);
        async16(ga + (size_t)(t + 256) * 8, &As[(t + 256) * 8]);
        async16(gb + (size_t)t * 8,         &Bs[t * 8]);
        async16(gb + (size_t)(t + 256) * 8, &Bs[(t + 256) * 8]);
        __syncthreads();

        bf16x8 a[4], b[4];
        #pragma unroll
        for (int i = 0; i < 4; ++i) a[i] = *(const bf16x8*)&As[(wr + i * 16 + lr) * 32 + lq * 8];
        #pragma unroll
        for (int i = 0; i < 4; ++i) b[i] = *(const bf16x8*)&Bs[(wc + i * 16 + lr) * 32 + lq * 8];
        #pragma unroll
        for (int i = 0; i < 4; ++i)
            #pragma unroll
            for (int j = 0; j < 4; ++j)
                acc[i][j] = __builtin_amdgcn_mfma_f32_16x16x32_bf16(a[i], b[j], acc[i][j], 0, 0, 0);
    }

    #pragma unroll
    for (int i = 0; i < 4; ++i) {
        #pragma unroll
        for (int j = 0; j < 4; ++j) {
            const int col  = n0 + wc + j * 16 + lr;
            const float bb = biasS[wc + j * 16 + lr];
            #pragma unroll
            for (int r = 0; r < 4; ++r) {
                const int row = m0 + wr + i * 16 + lq * 4 + r;
                if (row < M_ROWS)
                    qkv[(size_t)row * NQKV + col] = f2bf(acc[i][j][r] + bb);
            }
        }
    }
}

// ---------- kernel 4: attention — one wave per (frame,head), MFMA 32x32x16 ----------
// J=17 padded to 32: A/B rows clamped to row 0 (garbage rows masked or never
// stored), padded score COLUMNS masked to -inf pre-softmax.
// C/D layout (verified m74/m101): col=lane&31, row=(reg&3)+8*(reg>>2)+4*(lane>>5)
// A layout (extrapolated from verified 16x16x32): A[m=lane&31][k=8*(lane>>5)+j]

__global__ __launch_bounds__(256) void attn_k(const u16* __restrict__ qkv, u16* __restrict__ xa) {
    __shared__ u16 Pb[4][32 * 40];   // per-wave P buffer, row stride 40 u16 (80B)

    const int wv  = threadIdx.x >> 6;
    const int l   = threadIdx.x & 63;
    const int l31 = l & 31;
    const int hi  = l >> 5;

    const int id = blockIdx.x * 4 + wv;   // (frame, head) id
    const int f  = id >> 3;
    const int h  = id & 7;

    const int mrow = (l31 < 17) ? l31 : 0;             // clamp pad rows
    const u16* base = qkv + (size_t)(f * 17) * NQKV;
    const u16* Qp = base + (size_t)mrow * NQKV + h * 64 + 8 * hi;
    const u16* Kp = Qp + 512;

    // ---- S = Q K^T (scaled later), 4 MFMAs over d=64 ----
    f32x16 Sacc = {};
    #pragma unroll
    for (int c = 0; c < 4; ++c) {
        bf16x8 aq = *(const bf16x8*)(Qp + 16 * c);
        bf16x8 bk = *(const bf16x8*)(Kp + 16 * c);
        Sacc = __builtin_amdgcn_mfma_f32_32x32x16_bf16(aq, bk, Sacc, 0, 0, 0);
    }

    // ---- mask pad cols, softmax per row (row = per reg, 32-lane groups) ----
    float p[16];
    #pragma unroll
    for (int r = 0; r < 16; ++r)
        p[r] = (l31 < 17) ? Sacc[r] * 0.125f : -1e30f;

    #pragma unroll
    for (int r = 0; r < 16; ++r) {
        float mx = p[r];
        #pragma unroll
        for (int m = 1; m < 32; m <<= 1) mx = fmaxf(mx, __shfl_xor(mx, m));
        float e = __expf(p[r] - mx);
        float s = e;
        #pragma unroll
        for (int m = 1; m < 32; m <<= 1) s += __shfl_xor(s, m);
        p[r] = e * __builtin_amdgcn_rcpf(s);
    }

    // ---- sequential hierarchical triplets, in-register via readlane ----
    // value S[row j][col c] lives at reg=(j&3)|((j>>3)<<2), lane=c+32*((j>>2)&1)
    {
        constexpr int TJP[13] = {0,1,0,4,0,7,8,7,8,11,7,8,14};
        constexpr int TJ [13] = {1,2,4,5,7,8,9,8,11,12,8,14,15};
        constexpr int TJC[13] = {2,3,5,6,8,9,10,11,12,13,14,15,16};
        #pragma unroll
        for (int tr = 0; tr < 13; ++tr) {
            const int jp = TJP[tr], j = TJ[tr], jc = TJC[tr];
            const int rj = (j  & 3) | ((j  >> 3) << 2), hj = (j  >> 2) & 1;
            const int rc = (jc & 3) | ((jc >> 3) << 2), hc = (jc >> 2) & 1;
            const float half = 0.5f * __shfl(p[rj], jp + 32 * hj);
            if (l == jc + 32 * hj) p[rj] += half;   // S[j][jc] += half
            if (l == j  + 32 * hc) p[rc] += half;   // S[jc][j] += half
        }
    }

    // ---- C-layout -> A-layout via per-wave LDS round trip (bf16) ----
    u16* Pw = Pb[wv];
    #pragma unroll
    for (int r = 0; r < 16; ++r) {
        const int row = (r & 3) + 8 * (r >> 2) + 4 * hi;
        Pw[row * 40 + l31] = f2bf(p[r]);
    }
    asm volatile("s_waitcnt lgkmcnt(0)" ::: "memory");

    bf16x8 pa[2];
    #pragma unroll
    for (int c = 0; c < 2; ++c)
        pa[c] = *(const bf16x8*)&Pw[l31 * 40 + 16 * c + 8 * hi];

    // ---- O = P V, 2 n-tiles x 2 k-chunks of MFMA ----
    const u16* Vbase = base + 1024 + h * 64;
    f32x16 O[2] = {};
    #pragma unroll
    for (int t = 0; t < 2; ++t) {
        #pragma unroll
        for (int c = 0; c < 2; ++c) {
            u16 vv[8];
            #pragma unroll
            for (int j = 0; j < 8; ++j) {
                const int k  = 16 * c + 8 * hi + j;
                const int kr = (k < 17) ? k : 0;      // P cols >=17 are 0
                vv[j] = Vbase[(size_t)kr * NQKV + t * 32 + l31];
            }
            O[t] = __builtin_amdgcn_mfma_f32_32x32x16_bf16(pa[c], *(const bf16x8*)vv, O[t], 0, 0, 0);
        }
    }

    // ---- store xa in gemm2's K-tiled layout [kt][m][32] ----
    #pragma unroll
    for (int t = 0; t < 2; ++t) {
        const int kt = h * 2 + t;
        #pragma unroll
        for (int r = 0; r < 16; ++r) {
            const int row = (r & 3) + 8 * (r >> 2) + 4 * hi;
            if (row < 17)
                xa[((size_t)kt * M_PAD + (f * 17 + row)) * 32 + l31] = f2bf(O[t][r]);
        }
    }
}

// ---------- kernel 5: proj GEMM (128x128 tile) + bias + residual -> y fp32 ----------

__global__ __launch_bounds__(256) void gemm2_gemm(const u16* __restrict__ xa,  // [16][M_PAD][32]
                                                  const u16* __restrict__ wt,  // [16][512][32]
                                                  const float* __restrict__ bproj,
                                                  const float* __restrict__ x,
                                                  float* __restrict__ y) {
    __shared__ u16 As[128 * 32];
    __shared__ u16 Bs[128 * 32];
    __shared__ float biasS[128];

    const int n0 = blockIdx.x * 128;
    const int m0 = blockIdx.y * 128;
    const int t  = threadIdx.x;
    const int w  = t >> 6, l = t & 63;
    const int lr = l & 15, lq = l >> 4;
    const int wr = (w >> 1) * 64, wc = (w & 1) * 64;

    if (t < 128) biasS[t] = bproj[n0 + t];

    f32x4 acc[4][4] = {};

    for (int kt = 0; kt < 16; ++kt) {
        __syncthreads();
        const u16* ga = xa + ((size_t)kt * M_PAD + m0) * 32;
        const u16* gb = wt + ((size_t)kt * C_DIM + n0) * 32;
        async16(ga + (size_t)t * 8,         &As[t * 8]);
        async16(ga + (size_t)(t + 256) * 8, &As[(t + 256) * 8]);
        async16(gb + (size_t)t * 8,         &Bs[t * 8]);
        async16(gb + (size_t)(t + 256) * 8, &Bs[(t + 256) * 8]);
        __syncthreads();

        bf16x8 a[4], b[4];
        #pragma unroll
        for (int i = 0; i < 4; ++i) a[i] = *(const bf16x8*)&As[(wr + i * 16 + lr) * 32 + lq * 8];
        #pragma unroll
        for (int i = 0; i < 4; ++i) b[i] = *(const bf16x8*)&Bs[(wc + i * 16 + lr) * 32 + lq * 8];
        #pragma unroll
        for (int i = 0; i < 4; ++i)
            #pragma unroll
            for (int j = 0; j < 4; ++j)
                acc[i][j] = __builtin_amdgcn_mfma_f32_16x16x32_bf16(a[i], b[j], acc[i][j], 0, 0, 0);
    }

    // y = acc + bias + x (residual), fp32
    #pragma unroll
    for (int i = 0; i < 4; ++i) {
        #pragma unroll
        for (int j = 0; j < 4; ++j) {
            const int col  = n0 + wc + j * 16 + lr;
            const float bb = biasS[wc + j * 16 + lr];
            #pragma unroll
            for (int r = 0; r < 4; ++r) {
                const int row = m0 + wr + i * 16 + lq * 4 + r;
                if (row < M_ROWS) {
                    const size_t idx = (size_t)row * C_DIM + col;
                    y[idx] = acc[i][j][r] + bb + x[idx];
                }
            }
        }
    }
}

// ---------- kernel 6: LayerNorm over last dim (512), one wave per row ----------

__global__ __launch_bounds__(256) void ln_k(const float* __restrict__ y, float* __restrict__ out) {
    const int row = blockIdx.x * 4 + (threadIdx.x >> 6);
    const int l   = threadIdx.x & 63;
    const float* p = y + (size_t)row * C_DIM + l * 8;
    float4 a = *(const float4*)p;
    float4 b = *(const float4*)(p + 4);
    float s  = a.x + a.y + a.z + a.w + b.x + b.y + b.z + b.w;
    float sq = a.x*a.x + a.y*a.y + a.z*a.z + a.w*a.w
             + b.x*b.x + b.y*b.y + b.z*b.z + b.w*b.w;
    #pragma unroll
    for (int m = 1; m < 64; m <<= 1) {
        s  += __shfl_xor(s, m);
        sq += __shfl_xor(sq, m);
    }
    const float mean = s * (1.f / 512.f);
    const float var  = sq * (1.f / 512.f) - mean * mean;
    const float rstd = rsqrtf(var + 1e-5f);
    float* q = out + (size_t)row * C_DIM + l * 8;
    float4 o1, o2;
    o1.x = (a.x - mean) * rstd; o1.y = (a.y - mean) * rstd;
    o1.z = (a.z - mean) * rstd; o1.w = (a.w - mean) * rstd;
    o2.x = (b.x - mean) * rstd; o2.y = (b.y - mean) * rstd;
    o2.z = (b.z - mean) * rstd; o2.w = (b.w - mean) * rstd;
    *(float4*)q = o1;
    *(float4*)(q + 4) = o2;
}

// ---------- launch ----------

extern "C" void kernel_launch(void* const* d_in, const int* in_sizes, int n_in,
                              void* d_out, int out_size, void* d_ws, size_t ws_size,
                              hipStream_t stream) {
    const float* x     = (const float*)d_in[0];
    const float* Wqkv  = (const float*)d_in[1];
    const float* bqkv  = (const float*)d_in[2];
    const float* Wproj = (const float*)d_in[3];
    const float* bproj = (const float*)d_in[4];
    float* out = (float*)d_out;

    u16* xb  = (u16*)d_ws;                              // M_PAD*512
    u16* wqt = xb  + (size_t)M_PAD * C_DIM;             // 1536*512
    u16* wpt = wqt + (size_t)NQKV * C_DIM;              // 512*512
    u16* qkv = wpt + (size_t)C_DIM * C_DIM;             // M_PAD*1536 (bf16)
    u16* xa  = qkv + (size_t)M_PAD * NQKV;              // M_PAD*512
    // y (fp32, M_ROWS*512 = 135 MB) reuses the qkv region (203 MB, dead after attn)
    float* y = (float*)qkv;

    cast_x<<<(M_PAD * 64) / 256, 256, 0, stream>>>(x, xb);
    cast_w<<<dim3(NQKV / 64, 16), 256, 0, stream>>>(Wqkv, wqt, NQKV);
    cast_w<<<dim3(C_DIM / 64, 16), 256, 0, stream>>>(Wproj, wpt, C_DIM);
    gemm1<<<dim3(NQKV / 128, M_PAD / 128), 256, 0, stream>>>(xb, wqt, bqkv, qkv);
    attn_k<<<(NFRAME * 8) / 4, 256, 0, stream>>>(qkv, xa);
    gemm2_gemm<<<dim3(C_DIM / 128, M_PAD / 128), 256, 0, stream>>>(xa, wpt, bproj, x, y);
    ln_k<<<M_ROWS / 4, 256, 0, stream>>>(y, out);
}